// Round 2
// baseline (289.866 us; speedup 1.0000x reference)
//
#include <hip/hip_runtime.h>
#include <stdint.h>
#include <stddef.h>

#define TEMP      0.05f
#define INV_TEMP  20.0f     // 1/TEMP
#define MOMENTUM  0.2f
#define SMOOTH    0.1f
#define TAU_W     0.09f
#define NSAMP     100000
#define NFEAT     256
#define BATCH     256
#define SHIFT     20.0f     // fixed logit shift: |dot/TEMP| <= ~20.2, so exp(l-20) never overflows
#define MT        64        // feature rows per block in k_main

typedef float  f32x4  __attribute__((ext_vector_type(4)));
typedef float  f32x2  __attribute__((ext_vector_type(2)));
typedef short  short8 __attribute__((ext_vector_type(8)));
typedef unsigned int u32x2 __attribute__((ext_vector_type(2)));

// fp32 -> bf16 round-to-nearest-even (inputs are normal floats; no NaN handling needed)
__device__ __forceinline__ short f2bf(float f) {
    uint32_t u = __builtin_bit_cast(uint32_t, f);
    u = (u + 0x7fffu + ((u >> 16) & 1u)) >> 16;
    return (short)u;
}

// D = A*B + D, 16x16x32 bf16. Inline asm sidesteps builtin signature (short8 vs bf16x8) ambiguity.
__device__ __forceinline__ void mfma_bf16(f32x4& c, short8 a, short8 b) {
    asm("v_mfma_f32_16x16x32_bf16 %0, %1, %2, %0" : "+v"(c) : "v"(a), "v"(b));
}

// 256-thread (4-wave) block sum reduction; scratch needs >= 5 floats
__device__ __forceinline__ float block_reduce_sum256(float v, float* scratch) {
    for (int o = 32; o > 0; o >>= 1) v += __shfl_down(v, o, 64);
    int lane = threadIdx.x & 63, wid = threadIdx.x >> 6;
    if (lane == 0) scratch[wid] = v;
    __syncthreads();
    if (threadIdx.x == 0)
        scratch[4] = scratch[0] + scratch[1] + scratch[2] + scratch[3];
    __syncthreads();
    return scratch[4];
}

// ---------------------------------------------------------------------------
// K1: normalize x1/x2, emit bf16 X (pair-interleaved layout), exact d[b], zero accums.
// X layout: group g = b/32 owns rows [g*64, g*64+64): rows g*64 + (b%32)      = x1n[b]
//                                                     rows g*64 + 32 + (b%32) = x2n[b]
// => wave w of k_main (cols w*64..w*64+63) has matched x1/x2 pairs in-wave.
// ---------------------------------------------------------------------------
__global__ void k_prep(const float* __restrict__ in1, const float* __restrict__ in2,
                       const float* __restrict__ F, const int* __restrict__ tgt,
                       float* __restrict__ x1n, short* __restrict__ Xb,
                       float* __restrict__ dvec,
                       float* __restrict__ Z1, float* __restrict__ Z2, float* __restrict__ S12) {
    __shared__ float scratch[8];
    int b = blockIdx.x;
    int k = threadIdx.x;
    float v1 = in1[b * NFEAT + k];
    float v2 = in2[b * NFEAT + k];
    float n1 = block_reduce_sum256(v1 * v1, scratch);
    float n2 = block_reduce_sum256(v2 * v2, scratch);
    float x1 = v1 / fmaxf(sqrtf(n1), 1e-12f);
    float x2 = v2 / fmaxf(sqrtf(n2), 1e-12f);
    x1n[b * NFEAT + k] = x1;
    int g = b >> 5, r = b & 31;
    Xb[(g * 64 + r) * NFEAT + k]      = f2bf(x1);
    Xb[(g * 64 + 32 + r) * NFEAT + k] = f2bf(x2);
    int t = tgt[b];
    float dv = block_reduce_sum256(x1 * F[(size_t)t * NFEAT + k], scratch);
    if (k == 0) {
        dvec[b] = dv;
        Z1[b] = 0.f; Z2[b] = 0.f; S12[b] = 0.f;
    }
}

// ---------------------------------------------------------------------------
// K2: fused { F copy to d_out } + { bf16 MFMA logits } + { shifted-exp reductions }.
// Block: 512 threads = 8 waves; 64 F rows staged fp32->bf16 into XOR-swizzled LDS.
// Wave w handles X rows [w*64, w*64+64): col-frags 0,1 = x1 (b = w*32+cf*16+l15),
// col-frags 2,3 = x2 of the SAME b => S12 pairing is intra-lane.
// ---------------------------------------------------------------------------
__global__ void __launch_bounds__(512)
k_main(const float* __restrict__ F, const short* __restrict__ Xb,
       float* __restrict__ out,
       float* __restrict__ Z1, float* __restrict__ Z2, float* __restrict__ S12) {
    __shared__ short lfs[MT * NFEAT];  // 32 KB, row stride 512 B, bytes XOR-swizzled by ((row&7)<<4)
    int tid = threadIdx.x;
    int m0 = blockIdx.x * MT;

    // ---- stage F tile (fp32 -> bf16 -> LDS) + write-through exact fp32 copy ----
    // 64 rows * 64 float4-chunks = 4096 chunks, 512 threads -> 8 rounds
    #pragma unroll
    for (int rr = 0; rr < 8; ++rr) {
        int c   = rr * 512 + tid;
        int row = c >> 6, cc = c & 63;
        int grow = m0 + row;
        f32x4 v = {0.f, 0.f, 0.f, 0.f};
        if (grow < NSAMP)
            v = *(const f32x4*)(F + (size_t)grow * NFEAT + cc * 4);
        uint32_t p0 = (uint32_t)(uint16_t)f2bf(v[0]) | ((uint32_t)(uint16_t)f2bf(v[1]) << 16);
        uint32_t p1 = (uint32_t)(uint16_t)f2bf(v[2]) | ((uint32_t)(uint16_t)f2bf(v[3]) << 16);
        int off = row * 512 + ((cc * 8) ^ ((row & 7) << 4));
        *(u32x2*)((char*)lfs + off) = (u32x2){p0, p1};
        if (grow < NSAMP) {
            // d_out data region starts at +2 floats -> only 8B-aligned: use float2 stores
            float* op = out + 2 + (size_t)grow * NFEAT + cc * 4;
            *(f32x2*)op       = (f32x2){v[0], v[1]};
            *(f32x2*)(op + 2) = (f32x2){v[2], v[3]};
        }
    }
    __syncthreads();

    int w = tid >> 6, lane = tid & 63;
    int l15 = lane & 15, lg = lane >> 4;

    f32x4 acc[4][4] = {};  // [m-frag][col-frag]
    const short* xbase = Xb + (size_t)(w * 64) * NFEAT;

    #pragma unroll
    for (int kk = 0; kk < 8; ++kk) {       // K = 256 in steps of 32
        int kb = kk * 64 + lg * 16;        // byte offset of this lane-group's 8 bf16 k-elems
        short8 a[4], bf[4];
        #pragma unroll
        for (int cf = 0; cf < 4; ++cf)
            bf[cf] = *(const short8*)(xbase + (cf * 16 + l15) * NFEAT + kk * 32 + lg * 8);
        #pragma unroll
        for (int mf = 0; mf < 4; ++mf) {
            int row = mf * 16 + l15;
            a[mf] = *(const short8*)((const char*)lfs + row * 512 + (kb ^ ((row & 7) << 4)));
        }
        #pragma unroll
        for (int mf = 0; mf < 4; ++mf)
            #pragma unroll
            for (int cf = 0; cf < 4; ++cf)
                mfma_bf16(acc[mf][cf], a[mf], bf[cf]);
    }

    // ---- epilogue: fixed-shift exp + per-b reduction + atomics ----
    // C/D layout (m89): col = lane&15, row = (lane>>4)*4 + q
    #pragma unroll
    for (int cf = 0; cf < 2; ++cf) {
        float z1 = 0.f, z2 = 0.f, s12 = 0.f;
        #pragma unroll
        for (int mf = 0; mf < 4; ++mf) {
            #pragma unroll
            for (int q = 0; q < 4; ++q) {
                int grow = m0 + mf * 16 + lg * 4 + q;
                if (grow < NSAMP) {
                    float l1 = acc[mf][cf][q] * INV_TEMP;
                    float e1 = __expf(l1 - SHIFT);
                    float e2 = __expf(acc[mf][cf + 2][q] * INV_TEMP - SHIFT);
                    z1 += e1; z2 += e2; s12 += e2 * l1;
                }
            }
        }
        z1  += __shfl_xor(z1, 16);  z1  += __shfl_xor(z1, 32);
        z2  += __shfl_xor(z2, 16);  z2  += __shfl_xor(z2, 32);
        s12 += __shfl_xor(s12, 16); s12 += __shfl_xor(s12, 32);
        if (lane < 16) {
            int b = w * 32 + cf * 16 + lane;
            atomicAdd(&Z1[b], z1);
            atomicAdd(&Z2[b], z2);
            atomicAdd(&S12[b], s12);
        }
    }
}

// ---------------------------------------------------------------------------
// K3: per-target-cluster weighted-mean update (exact fp32); overwrites copied rows.
// ---------------------------------------------------------------------------
__global__ void k_update(const float* __restrict__ F, const int* __restrict__ tgt,
                         const float* __restrict__ dvec, const float* __restrict__ x1n,
                         float* __restrict__ out) {
    __shared__ float scratch[8];
    int b = blockIdx.x, k = threadIdx.x;
    int t = tgt[b];
    for (int bp = 0; bp < b; ++bp)
        if (tgt[bp] == t) return;  // only first occurrence handles this cluster (uniform branch)
    float m = -1e30f;
    for (int bp = 0; bp < BATCH; ++bp)
        if (tgt[bp] == t) m = fmaxf(m, -dvec[bp] / TAU_W);
    float denom = 0.f;
    for (int bp = 0; bp < BATCH; ++bp)
        if (tgt[bp] == t) denom += expf(-dvec[bp] / TAU_W - m);
    float wmean = 0.f;
    for (int bp = 0; bp < BATCH; ++bp)
        if (tgt[bp] == t) {
            float wq = expf(-dvec[bp] / TAU_W - m) / denom;
            wmean += wq * x1n[bp * NFEAT + k];
        }
    float upd = MOMENTUM * F[(size_t)t * NFEAT + k] + (1.f - MOMENTUM) * wmean;
    float nrm = block_reduce_sum256(upd * upd, scratch);
    out[2 + (size_t)t * NFEAT + k] = upd / fmaxf(sqrtf(nrm), 1e-12f);
}

// ---------------------------------------------------------------------------
// K4: closed-form losses from the per-b statistics.
// ---------------------------------------------------------------------------
__global__ void k_loss(const float* __restrict__ dvec, const float* __restrict__ Z1,
                       const float* __restrict__ Z2, const float* __restrict__ S12,
                       float* __restrict__ out) {
    __shared__ float scratch[8];
    int b = threadIdx.x;
    float L1   = SHIFT + logf(Z1[b]);           // logsumexp of logits1 row b
    float lpt  = dvec[b] * INV_TEMP - L1;       // logp at target
    float ce12 = S12[b] / Z2[b];                // sum_n softmax(l2) * l1
    float lc = -lpt;
    float ls = (1.f - SMOOTH) * (L1 - ce12) + SMOOTH * (-lpt);
    float sc = block_reduce_sum256(lc, scratch);
    float ss = block_reduce_sum256(ls, scratch);
    if (b == 0) {
        out[0] = sc / (float)BATCH;
        out[1] = ss / (float)BATCH;
    }
}

extern "C" void kernel_launch(void* const* d_in, const int* in_sizes, int n_in,
                              void* d_out, int out_size, void* d_ws, size_t ws_size,
                              hipStream_t stream) {
    const float* in1 = (const float*)d_in[0];
    const float* in2 = (const float*)d_in[1];
    const float* F   = (const float*)d_in[2];
    const int*   tgt = (const int*)d_in[3];
    float* out = (float*)d_out;

    char* ws = (char*)d_ws;
    float* x1n = (float*)ws;                   // 256*256*4   = 262144 B
    short* Xb  = (short*)(ws + 262144);        // 512*256*2   = 262144 B
    float* dv  = (float*)(ws + 524288);        // 1 KB
    float* Z1  = (float*)(ws + 525312);        // 1 KB
    float* Z2  = (float*)(ws + 526336);        // 1 KB
    float* S12 = (float*)(ws + 527360);        // 1 KB

    hipLaunchKernelGGL(k_prep, dim3(BATCH), dim3(256), 0, stream,
                       in1, in2, F, tgt, x1n, Xb, dv, Z1, Z2, S12);
    hipLaunchKernelGGL(k_main, dim3((NSAMP + MT - 1) / MT), dim3(512), 0, stream,
                       F, Xb, out, Z1, Z2, S12);
    hipLaunchKernelGGL(k_update, dim3(BATCH), dim3(256), 0, stream,
                       F, tgt, dv, x1n, out);
    hipLaunchKernelGGL(k_loss, dim3(1), dim3(256), 0, stream,
                       dv, Z1, Z2, S12, out);
}